// Round 5
// baseline (1456.243 us; speedup 1.0000x reference)
//
#include <hip/hip_runtime.h>
#include <math.h>

// Problem constants
#define BB 2
#define NDIM 64      // D = H = W = 64
#define CC 128       // channels
#define WR 33        // rfft bins along W
#define NBLK 8
#define BSZ 16

static constexpr float LAM = 0.01f;            // softshrink lambda
static constexpr float ORTHO = 1.0f / 512.0f;  // 1/sqrt(64^3)
static constexpr float TWO_PI_64 = 6.28318530717958647692f / 64.0f;

// LDS row stride (in float2) for one 64-elem transform: pad 64 -> 66.
#define LROW 66

// Spectrum element strides (uint32 units), layout (b, d, h, wr, c)
#define S_WRs 128L
#define S_Hs 4224L      // 33*128
#define S_Ds 270336L    // 64*4224
#define S_Bs 17301504L  // 64*270336

__device__ inline float2 cmulf(float2 a, float2 b) {
    return make_float2(a.x * b.x - a.y * b.y, a.x * b.y + a.y * b.x);
}

// bf16 pack/unpack (RNE). re in low 16, im in high 16.
__device__ inline unsigned pack_c(float2 v) {
    unsigned ua = __float_as_uint(v.x), ub = __float_as_uint(v.y);
    ua += 0x7fffu + ((ua >> 16) & 1u);
    ub += 0x7fffu + ((ub >> 16) & 1u);
    return (ua >> 16) | (ub & 0xffff0000u);
}
__device__ inline float2 unpack_c(unsigned u) {
    return make_float2(__uint_as_float(u << 16), __uint_as_float(u & 0xffff0000u));
}

// Naive fully-unrolled 8-point DFT. DIR = -1 forward, +1 inverse.
template <int DIR>
__device__ inline void dft8(const float2 v[8], float2 y[8]) {
    const float s = 0.70710678118654752440f;
    float2 T[8];
    T[0] = make_float2(1.f, 0.f);
    T[1] = make_float2(s, DIR * s);
    T[2] = make_float2(0.f, DIR * 1.f);
    T[3] = make_float2(-s, DIR * s);
    T[4] = make_float2(-1.f, 0.f);
    T[5] = make_float2(-s, -DIR * s);
    T[6] = make_float2(0.f, -DIR * 1.f);
    T[7] = make_float2(s, -DIR * s);
#pragma unroll
    for (int k = 0; k < 8; k++) {
        float2 acc = v[0];
#pragma unroll
        for (int j = 1; j < 8; j++) {
            float2 t = T[(j * k) & 7];
            acc.x += v[j].x * t.x - v[j].y * t.y;
            acc.y += v[j].x * t.y + v[j].y * t.x;
        }
        y[k] = acc;
    }
}

// Per-thread twiddles for its p = t&7: tw[k1-1] = (cos, sin)(+2*pi*p*k1/64)
__device__ inline void make_tw(int p, float2 tw[7]) {
#pragma unroll
    for (int k1 = 1; k1 < 8; k1++) {
        float ang = TWO_PI_64 * (float)(p * k1);
        float sn, cs;
        __sincosf(ang, &sn, &cs);
        tw[k1 - 1] = make_float2(cs, sn);
    }
}

// 64-pt FFT on 64 contiguous float2 in LDS (base), cooperatively by 8 threads
// p = 0..7. Natural order in, natural order out.
// Caller must __syncthreads() after this before other threads consume results.
template <int DIR>
__device__ inline void fft64_lds(float2* base, int p, const float2 tw[7]) {
    float2 v[8], a[8];
#pragma unroll
    for (int n1 = 0; n1 < 8; n1++) v[n1] = base[8 * n1 + p];
    dft8<DIR>(v, a);
#pragma unroll
    for (int k1 = 1; k1 < 8; k1++) {
        float2 w = make_float2(tw[k1 - 1].x, (float)DIR * tw[k1 - 1].y);
        a[k1] = cmulf(a[k1], w);
    }
#pragma unroll
    for (int k1 = 0; k1 < 8; k1++) base[8 * k1 + p] = a[k1];
    __syncthreads();
    float2 u[8], y[8];
#pragma unroll
    for (int n2 = 0; n2 < 8; n2++) u[n2] = base[8 * p + n2];
    dft8<DIR>(u, y);
    __syncthreads();
#pragma unroll
    for (int k2 = 0; k2 < 8; k2++) base[8 * k2 + p] = y[k2];  // holds X[p + 8*k2]
}

// ---------------- Pass 1: rfft along W. x f32 -> buf (b,d,h,wr,c) packed bf16
__global__ __launch_bounds__(256) void k_rfft_w(const float* __restrict__ x,
                                                unsigned* __restrict__ buf) {
    __shared__ float2 lds[32 * LROW];
    const int t = threadIdx.x;
    const size_t bdh = blockIdx.x;
    const float* xp = x + bdh * (size_t)(NDIM * CC);
    unsigned* op = buf + bdh * (size_t)(WR * CC);
    float2 tw[7];
    make_tw(t & 7, tw);
    for (int chunk = 0; chunk < 4; chunk++) {
        const int c0 = chunk * 32;
#pragma unroll
        for (int k = 0; k < 8; k++) {
            int i = k * 256 + t;
            int c = i & 31, w = i >> 5;
            float vv = xp[(size_t)w * CC + c0 + c] * ORTHO;
            lds[c * LROW + w] = make_float2(vv, 0.f);
        }
        __syncthreads();
        fft64_lds<-1>(&lds[(t >> 3) * LROW], t & 7, tw);
        __syncthreads();
        for (int i = t; i < WR * 32; i += 256) {
            int c = i & 31, kk = i >> 5;
            op[(size_t)kk * CC + c0 + c] = pack_c(lds[c * LROW + kk]);
        }
        __syncthreads();
    }
}

// ---------------- Passes 2,3,5,6: in-place complex FFT along a strided axis.
template <int DIR>
__global__ __launch_bounds__(256) void k_fft_axis(unsigned* __restrict__ buf, int outerB,
                                                  long sA, long sB, long sAxis) {
    __shared__ float2 lds[32 * LROW];
    const int t = threadIdx.x;
    const long a = blockIdx.x / outerB;
    const long ob = blockIdx.x % outerB;
    unsigned* p0 = buf + a * sA + ob * sB;
    float2 tw[7];
    make_tw(t & 7, tw);
    for (int chunk = 0; chunk < 4; chunk++) {
        const int c0 = chunk * 32;
#pragma unroll
        for (int k = 0; k < 8; k++) {
            int i = k * 256 + t;
            int c = i & 31, n = i >> 5;
            lds[c * LROW + n] = unpack_c(p0[(long)n * sAxis + c0 + c]);
        }
        __syncthreads();
        fft64_lds<DIR>(&lds[(t >> 3) * LROW], t & 7, tw);
        __syncthreads();
#pragma unroll
        for (int k = 0; k < 8; k++) {
            int i = k * 256 + t;
            int c = i & 31, n = i >> 5;
            p0[(long)n * sAxis + c0 + c] = pack_c(lds[c * LROW + n]);
        }
        __syncthreads();
    }
}

// ---------------- Pass 4: block-diag complex MLP + softshrink, in place.
// Block = 64 spectral points x 128 channels, staged packed in LDS (33 KB).
// Thread = (pt, blk-pair); weights via wave-uniform scalar loads.
#define MP 129  // LDS pitch in u32: bank = (pt + k) % 32 -> 2-way (free)
__global__ __launch_bounds__(256) void k_mlp(unsigned* __restrict__ buf,
                                             const float* __restrict__ w1,
                                             const float* __restrict__ b1,
                                             const float* __restrict__ w2,
                                             const float* __restrict__ b2) {
    __shared__ unsigned S[64 * MP];
    const int t = threadIdx.x;
    unsigned* p0 = buf + (size_t)blockIdx.x * (64 * CC);
    // stage: coalesced, packed (no unpack)
#pragma unroll
    for (int k = 0; k < 32; k++) {
        int idx = k * 256 + t;  // 0..8191
        int pt = idx >> 7, c = idx & 127;
        S[pt * MP + c] = p0[idx];
    }
    __syncthreads();
    const int pt = t & 63;
    const int blk0 = t >> 6;  // 0..3, wave-uniform
#pragma unroll 1
    for (int bq = 0; bq < 2; bq++) {
        const int blk = __builtin_amdgcn_readfirstlane(blk0 + 4 * bq);  // 0..7
        const float* W1r = w1 + (size_t)blk * 256;
        const float* W1i = w1 + 2048 + (size_t)blk * 256;
        const float* W2r = w2 + (size_t)blk * 256;
        const float* W2i = w2 + 2048 + (size_t)blk * 256;

        float xr[16], xi[16];
#pragma unroll
        for (int i = 0; i < 16; i++) {
            float2 v = unpack_c(S[pt * MP + blk * 16 + i]);
            xr[i] = v.x;
            xi[i] = v.y;
        }
        float o1r[16], o1i[16];
#pragma unroll
        for (int o = 0; o < 16; o++) {
            o1r[o] = b1[blk * 16 + o];
            o1i[o] = b1[128 + blk * 16 + o];
        }
#pragma unroll
        for (int i = 0; i < 16; i++) {
#pragma unroll
            for (int o = 0; o < 16; o++) {
                float wr_ = W1r[i * 16 + o], wi_ = W1i[i * 16 + o];
                o1r[o] += xr[i] * wr_ - xi[i] * wi_;
                o1i[o] += xi[i] * wr_ + xr[i] * wi_;
            }
        }
#pragma unroll
        for (int o = 0; o < 16; o++) {
            o1r[o] = fmaxf(o1r[o], 0.f);
            o1i[o] = fmaxf(o1i[o], 0.f);
        }
        // layer 2: per-output accumulate (keeps register pressure low);
        // owner-computes: this thread reads/writes only its own (pt, blk) slice.
#pragma unroll
        for (int o = 0; o < 16; o++) {
            float sr = b2[blk * 16 + o], si = b2[128 + blk * 16 + o];
#pragma unroll
            for (int i = 0; i < 16; i++) {
                float wr_ = W2r[i * 16 + o], wi_ = W2i[i * 16 + o];
                sr += o1r[i] * wr_ - o1i[i] * wi_;
                si += o1i[i] * wr_ + o1r[i] * wi_;
            }
            sr = (sr > LAM) ? (sr - LAM) : ((sr < -LAM) ? (sr + LAM) : 0.f);
            si = (si > LAM) ? (si - LAM) : ((si < -LAM) ? (si + LAM) : 0.f);
            S[pt * MP + blk * 16 + o] = pack_c(make_float2(sr, si));
        }
    }
    __syncthreads();
    // store: coalesced, packed
#pragma unroll
    for (int k = 0; k < 32; k++) {
        int idx = k * 256 + t;
        int pt2 = idx >> 7, c = idx & 127;
        p0[idx] = S[pt2 * MP + c];
    }
}

// ---------------- Pass 7: irfft along W + residual.
__global__ __launch_bounds__(256) void k_irfft_w(const unsigned* __restrict__ buf,
                                                 const float* __restrict__ x,
                                                 float* __restrict__ out) {
    __shared__ float2 lds[32 * LROW];
    const int t = threadIdx.x;
    const size_t bdh = blockIdx.x;
    const unsigned* ip = buf + bdh * (size_t)(WR * CC);
    const float* xp = x + bdh * (size_t)(NDIM * CC);
    float* op = out + bdh * (size_t)(NDIM * CC);
    float2 tw[7];
    make_tw(t & 7, tw);
    for (int chunk = 0; chunk < 4; chunk++) {
        const int c0 = chunk * 32;
        for (int i = t; i < WR * 32; i += 256) {
            int c = i & 31, kk = i >> 5;
            lds[c * LROW + kk] = unpack_c(ip[(size_t)kk * CC + c0 + c]);
        }
        __syncthreads();
        // Hermitian fill: X[64-k] = conj(X[k]) for k=1..31
        for (int i = t; i < 31 * 32; i += 256) {
            int c = i & 31, kk = 33 + (i >> 5);
            float2 v = lds[c * LROW + (64 - kk)];
            lds[c * LROW + kk] = make_float2(v.x, -v.y);
        }
        __syncthreads();
        fft64_lds<1>(&lds[(t >> 3) * LROW], t & 7, tw);
        __syncthreads();
#pragma unroll
        for (int k = 0; k < 8; k++) {
            int i = k * 256 + t;
            int c = i & 31, w = i >> 5;
            size_t gi = (size_t)w * CC + c0 + c;
            op[gi] = lds[c * LROW + w].x * ORTHO + xp[gi];
        }
        __syncthreads();
    }
}

extern "C" void kernel_launch(void* const* d_in, const int* in_sizes, int n_in,
                              void* d_out, int out_size, void* d_ws, size_t ws_size,
                              hipStream_t stream) {
    const float* x = (const float*)d_in[0];
    const float* w1 = (const float*)d_in[1];
    const float* b1 = (const float*)d_in[2];
    const float* w2 = (const float*)d_in[3];
    const float* b2 = (const float*)d_in[4];
    float* out = (float*)d_out;
    unsigned* buf = (unsigned*)d_ws;  // B*D*H*WR*C u32 = 138.4 MB (L3-resident)

    // 1) rfft along W
    k_rfft_w<<<BB * NDIM * NDIM, 256, 0, stream>>>(x, buf);
    // 2) FFT along H: per (b,d,wr)
    k_fft_axis<-1><<<BB * NDIM * WR, 256, 0, stream>>>(buf, WR, S_Ds, S_WRs, S_Hs);
    // 3) FFT along D: per (b,h,wr)
    k_fft_axis<-1><<<BB * NDIM * WR, 256, 0, stream>>>(buf, NDIM * WR, S_Bs, S_WRs, S_Ds);
    // 4) block-diagonal complex MLP + softshrink (in place, 64 pts per block)
    k_mlp<<<(BB * NDIM * NDIM * WR) / 64 * 64 / 64, 256, 0, stream>>>(buf, w1, b1, w2, b2);
    // 5) inverse FFT along D
    k_fft_axis<1><<<BB * NDIM * WR, 256, 0, stream>>>(buf, NDIM * WR, S_Bs, S_WRs, S_Ds);
    // 6) inverse FFT along H
    k_fft_axis<1><<<BB * NDIM * WR, 256, 0, stream>>>(buf, WR, S_Ds, S_WRs, S_Hs);
    // 7) irfft along W + residual
    k_irfft_w<<<BB * NDIM * NDIM, 256, 0, stream>>>(buf, x, out);
}

// Round 6
// 953.113 us; speedup vs baseline: 1.5279x; 1.5279x over previous
//
#include <hip/hip_runtime.h>
#include <math.h>

// Problem constants
#define BB 2
#define NDIM 64      // D = H = W = 64
#define CC 128       // channels
#define WR 33        // rfft bins along W
#define NBLK 8
#define BSZ 16

static constexpr float LAM = 0.01f;            // softshrink lambda
static constexpr float ORTHO = 1.0f / 512.0f;  // 1/sqrt(64^3)
static constexpr float TWO_PI_64 = 6.28318530717958647692f / 64.0f;

// LDS row stride (in float2) for one 64-elem transform: pad 64 -> 66.
#define LROW 66

// Spectrum element strides (uint32 units), layout (b, d, h, wr, c)
#define S_WRs 128L
#define S_Hs 4224L      // 33*128
#define S_Ds 270336L    // 64*4224
#define S_Bs 17301504L  // 64*270336

typedef short bf16x8 __attribute__((ext_vector_type(8)));
typedef float f32x4v __attribute__((ext_vector_type(4)));

__device__ inline float2 cmulf(float2 a, float2 b) {
    return make_float2(a.x * b.x - a.y * b.y, a.x * b.y + a.y * b.x);
}

// bf16 pack/unpack (RNE). first elem in low 16, second in high 16.
__device__ inline unsigned pack_c(float2 v) {
    unsigned ua = __float_as_uint(v.x), ub = __float_as_uint(v.y);
    ua += 0x7fffu + ((ua >> 16) & 1u);
    ub += 0x7fffu + ((ub >> 16) & 1u);
    return (ua >> 16) | (ub & 0xffff0000u);
}
__device__ inline float2 unpack_c(unsigned u) {
    return make_float2(__uint_as_float(u << 16), __uint_as_float(u & 0xffff0000u));
}

// Naive fully-unrolled 8-point DFT. DIR = -1 forward, +1 inverse.
template <int DIR>
__device__ inline void dft8(const float2 v[8], float2 y[8]) {
    const float s = 0.70710678118654752440f;
    float2 T[8];
    T[0] = make_float2(1.f, 0.f);
    T[1] = make_float2(s, DIR * s);
    T[2] = make_float2(0.f, DIR * 1.f);
    T[3] = make_float2(-s, DIR * s);
    T[4] = make_float2(-1.f, 0.f);
    T[5] = make_float2(-s, -DIR * s);
    T[6] = make_float2(0.f, -DIR * 1.f);
    T[7] = make_float2(s, -DIR * s);
#pragma unroll
    for (int k = 0; k < 8; k++) {
        float2 acc = v[0];
#pragma unroll
        for (int j = 1; j < 8; j++) {
            float2 t = T[(j * k) & 7];
            acc.x += v[j].x * t.x - v[j].y * t.y;
            acc.y += v[j].x * t.y + v[j].y * t.x;
        }
        y[k] = acc;
    }
}

// Per-thread twiddles for its p = t&7: tw[k1-1] = (cos, sin)(+2*pi*p*k1/64)
__device__ inline void make_tw(int p, float2 tw[7]) {
#pragma unroll
    for (int k1 = 1; k1 < 8; k1++) {
        float ang = TWO_PI_64 * (float)(p * k1);
        float sn, cs;
        __sincosf(ang, &sn, &cs);
        tw[k1 - 1] = make_float2(cs, sn);
    }
}

// 64-pt FFT on 64 contiguous float2 in LDS (base), cooperatively by 8 threads
// p = 0..7. Natural order in, natural order out.
template <int DIR>
__device__ inline void fft64_lds(float2* base, int p, const float2 tw[7]) {
    float2 v[8], a[8];
#pragma unroll
    for (int n1 = 0; n1 < 8; n1++) v[n1] = base[8 * n1 + p];
    dft8<DIR>(v, a);
#pragma unroll
    for (int k1 = 1; k1 < 8; k1++) {
        float2 w = make_float2(tw[k1 - 1].x, (float)DIR * tw[k1 - 1].y);
        a[k1] = cmulf(a[k1], w);
    }
#pragma unroll
    for (int k1 = 0; k1 < 8; k1++) base[8 * k1 + p] = a[k1];
    __syncthreads();
    float2 u[8], y[8];
#pragma unroll
    for (int n2 = 0; n2 < 8; n2++) u[n2] = base[8 * p + n2];
    dft8<DIR>(u, y);
    __syncthreads();
#pragma unroll
    for (int k2 = 0; k2 < 8; k2++) base[8 * k2 + p] = y[k2];  // holds X[p + 8*k2]
}

// ---------------- Pass 1: rfft along W. x f32 -> buf (b,d,h,wr,c) packed bf16
__global__ __launch_bounds__(256) void k_rfft_w(const float* __restrict__ x,
                                                unsigned* __restrict__ buf) {
    __shared__ float2 lds[32 * LROW];
    const int t = threadIdx.x;
    const size_t bdh = blockIdx.x;
    const float* xp = x + bdh * (size_t)(NDIM * CC);
    unsigned* op = buf + bdh * (size_t)(WR * CC);
    float2 tw[7];
    make_tw(t & 7, tw);
    for (int chunk = 0; chunk < 4; chunk++) {
        const int c0 = chunk * 32;
#pragma unroll
        for (int k = 0; k < 8; k++) {
            int i = k * 256 + t;
            int c = i & 31, w = i >> 5;
            float vv = xp[(size_t)w * CC + c0 + c] * ORTHO;
            lds[c * LROW + w] = make_float2(vv, 0.f);
        }
        __syncthreads();
        fft64_lds<-1>(&lds[(t >> 3) * LROW], t & 7, tw);
        __syncthreads();
        for (int i = t; i < WR * 32; i += 256) {
            int c = i & 31, kk = i >> 5;
            op[(size_t)kk * CC + c0 + c] = pack_c(lds[c * LROW + kk]);
        }
        __syncthreads();
    }
}

// ---------------- Passes 2,3,5,6: in-place complex FFT along a strided axis.
template <int DIR>
__global__ __launch_bounds__(256) void k_fft_axis(unsigned* __restrict__ buf, int outerB,
                                                  long sA, long sB, long sAxis) {
    __shared__ float2 lds[32 * LROW];
    const int t = threadIdx.x;
    const long a = blockIdx.x / outerB;
    const long ob = blockIdx.x % outerB;
    unsigned* p0 = buf + a * sA + ob * sB;
    float2 tw[7];
    make_tw(t & 7, tw);
    for (int chunk = 0; chunk < 4; chunk++) {
        const int c0 = chunk * 32;
#pragma unroll
        for (int k = 0; k < 8; k++) {
            int i = k * 256 + t;
            int c = i & 31, n = i >> 5;
            lds[c * LROW + n] = unpack_c(p0[(long)n * sAxis + c0 + c]);
        }
        __syncthreads();
        fft64_lds<DIR>(&lds[(t >> 3) * LROW], t & 7, tw);
        __syncthreads();
#pragma unroll
        for (int k = 0; k < 8; k++) {
            int i = k * 256 + t;
            int c = i & 31, n = i >> 5;
            p0[(long)n * sAxis + c0 + c] = pack_c(lds[c * LROW + n]);
        }
        __syncthreads();
    }
}

// ---------------- Pass 4: block-diag complex MLP + softshrink, in place, via MFMA.
// Complex GEMM as real: [o_r|o_i] = [x_r|x_i] * [[Wr, Wi], [-Wi, Wr]].
// CTA = 256 threads = 4 waves; wave = 16 points x all 8 blocks.
// A/B frags both built by us with the SAME k-map (k = (lane>>4)*8 + elem), so
// any HW k-permutation cancels. C/D layout (col=lane&15, row=(lane>>4)*4+reg)
// is the HW-verified mapping.
__global__ __launch_bounds__(256) void k_mlp(unsigned* __restrict__ buf,
                                             const float* __restrict__ w1,
                                             const float* __restrict__ b1,
                                             const float* __restrict__ w2,
                                             const float* __restrict__ b2) {
    __shared__ uint4 WF[2048];          // [blk][layer][half][lane] -> 32 KB
    __shared__ float BIAS[512];         // b1r|b1i|b2r|b2i, 128 each
    __shared__ unsigned SHUF[4 * 272];  // per-wave 16 x (pitch 17)
    const int t = threadIdx.x;

    // Build B-fragments (bf16) once per CTA.
    for (int widx = t; widx < 2048; widx += 256) {
        const int lane = widx & 63;
        const int half = (widx >> 6) & 1;   // 0: real-out cols, 1: imag-out cols
        const float* ws = (widx & 128) ? w2 : w1;
        const int blk = widx >> 8;
        const int n = lane & 15;
        const int kc = lane >> 4;
        unsigned wrd[4];
#pragma unroll
        for (int j2 = 0; j2 < 4; j2++) {
            float v[2];
#pragma unroll
            for (int e = 0; e < 2; e++) {
                const int k = kc * 8 + j2 * 2 + e;
                float val;
                if (k < 16)
                    val = half ? ws[2048 + blk * 256 + k * 16 + n]
                               : ws[blk * 256 + k * 16 + n];
                else
                    val = half ? ws[blk * 256 + (k - 16) * 16 + n]
                               : -ws[2048 + blk * 256 + (k - 16) * 16 + n];
                v[e] = val;
            }
            wrd[j2] = pack_c(make_float2(v[0], v[1]));
        }
        WF[widx] = make_uint4(wrd[0], wrd[1], wrd[2], wrd[3]);
    }
    BIAS[t] = b1[t];        // t < 256 always
    BIAS[256 + t] = b2[t];
    __syncthreads();

    const int wv = t >> 6, l = t & 63;
    const int m = l & 15;          // A row / C col
    const int kc = l >> 4;         // 0..3 k-chunk
    const int c0 = (kc & 1) * 8;   // channel base within block
    const bool imh = kc >= 2;      // lanes 32-63 carry imaginary k-half
    unsigned* shuf = &SHUF[wv * 272];
    unsigned* pbase = buf + (size_t)(blockIdx.x * 64 + wv * 16) * CC;

#pragma unroll 1
    for (int blk = 0; blk < 8; blk++) {
        // ---- A gather (global, packed bf16 pairs)
        const unsigned* arow = pbase + (size_t)m * CC + blk * 16 + c0;
        const uint4 q0 = *(const uint4*)arow;
        const uint4 q1 = *(const uint4*)(arow + 4);
        union { unsigned w[4]; bf16x8 v; } A;
        if (!imh) {
            A.w[0] = (q0.x & 0xffffu) | (q0.y << 16);
            A.w[1] = (q0.z & 0xffffu) | (q0.w << 16);
            A.w[2] = (q1.x & 0xffffu) | (q1.y << 16);
            A.w[3] = (q1.z & 0xffffu) | (q1.w << 16);
        } else {
            A.w[0] = (q0.x >> 16) | (q0.y & 0xffff0000u);
            A.w[1] = (q0.z >> 16) | (q0.w & 0xffff0000u);
            A.w[2] = (q1.x >> 16) | (q1.y & 0xffff0000u);
            A.w[3] = (q1.z >> 16) | (q1.w & 0xffff0000u);
        }
        // ---- layer 1
        union { uint4 q; bf16x8 v; } B1r, B1i, B2r, B2i;
        B1r.q = WF[(blk * 4 + 0) * 64 + l];
        B1i.q = WF[(blk * 4 + 1) * 64 + l];
        f32x4v Dr = {0.f, 0.f, 0.f, 0.f}, Di = {0.f, 0.f, 0.f, 0.f};
        Dr = __builtin_amdgcn_mfma_f32_16x16x32_bf16(A.v, B1r.v, Dr, 0, 0, 0);
        Di = __builtin_amdgcn_mfma_f32_16x16x32_bf16(A.v, B1i.v, Di, 0, 0, 0);
        const float b1r_ = BIAS[blk * 16 + m];
        const float b1i_ = BIAS[128 + blk * 16 + m];
#pragma unroll
        for (int r = 0; r < 4; r++) {
            const float o1r = fmaxf(Dr[r] + b1r_, 0.f);
            const float o1i = fmaxf(Di[r] + b1i_, 0.f);
            shuf[(kc * 4 + r) * 17 + m] = pack_c(make_float2(o1r, o1i));
        }
        // ---- inter-layer redistribution (within-wave; compiler orders LDS deps)
        unsigned s[8];
#pragma unroll
        for (int j = 0; j < 8; j++) s[j] = shuf[m * 17 + c0 + j];
        union { unsigned w[4]; bf16x8 v; } A2;
        if (!imh) {
            A2.w[0] = (s[0] & 0xffffu) | (s[1] << 16);
            A2.w[1] = (s[2] & 0xffffu) | (s[3] << 16);
            A2.w[2] = (s[4] & 0xffffu) | (s[5] << 16);
            A2.w[3] = (s[6] & 0xffffu) | (s[7] << 16);
        } else {
            A2.w[0] = (s[0] >> 16) | (s[1] & 0xffff0000u);
            A2.w[1] = (s[2] >> 16) | (s[3] & 0xffff0000u);
            A2.w[2] = (s[4] >> 16) | (s[5] & 0xffff0000u);
            A2.w[3] = (s[6] >> 16) | (s[7] & 0xffff0000u);
        }
        // ---- layer 2
        B2r.q = WF[(blk * 4 + 2) * 64 + l];
        B2i.q = WF[(blk * 4 + 3) * 64 + l];
        f32x4v Er = {0.f, 0.f, 0.f, 0.f}, Ei = {0.f, 0.f, 0.f, 0.f};
        Er = __builtin_amdgcn_mfma_f32_16x16x32_bf16(A2.v, B2r.v, Er, 0, 0, 0);
        Ei = __builtin_amdgcn_mfma_f32_16x16x32_bf16(A2.v, B2i.v, Ei, 0, 0, 0);
        const float b2r_ = BIAS[256 + blk * 16 + m];
        const float b2i_ = BIAS[384 + blk * 16 + m];
#pragma unroll
        for (int r = 0; r < 4; r++) {
            float sr = Er[r] + b2r_, si = Ei[r] + b2i_;
            sr = (sr > LAM) ? (sr - LAM) : ((sr < -LAM) ? (sr + LAM) : 0.f);
            si = (si > LAM) ? (si - LAM) : ((si < -LAM) ? (si + LAM) : 0.f);
            pbase[(size_t)(kc * 4 + r) * CC + blk * 16 + m] =
                pack_c(make_float2(sr, si));
        }
    }
}

// ---------------- Pass 7: irfft along W + residual.
__global__ __launch_bounds__(256) void k_irfft_w(const unsigned* __restrict__ buf,
                                                 const float* __restrict__ x,
                                                 float* __restrict__ out) {
    __shared__ float2 lds[32 * LROW];
    const int t = threadIdx.x;
    const size_t bdh = blockIdx.x;
    const unsigned* ip = buf + bdh * (size_t)(WR * CC);
    const float* xp = x + bdh * (size_t)(NDIM * CC);
    float* op = out + bdh * (size_t)(NDIM * CC);
    float2 tw[7];
    make_tw(t & 7, tw);
    for (int chunk = 0; chunk < 4; chunk++) {
        const int c0 = chunk * 32;
        for (int i = t; i < WR * 32; i += 256) {
            int c = i & 31, kk = i >> 5;
            lds[c * LROW + kk] = unpack_c(ip[(size_t)kk * CC + c0 + c]);
        }
        __syncthreads();
        // Hermitian fill: X[64-k] = conj(X[k]) for k=1..31
        for (int i = t; i < 31 * 32; i += 256) {
            int c = i & 31, kk = 33 + (i >> 5);
            float2 v = lds[c * LROW + (64 - kk)];
            lds[c * LROW + kk] = make_float2(v.x, -v.y);
        }
        __syncthreads();
        fft64_lds<1>(&lds[(t >> 3) * LROW], t & 7, tw);
        __syncthreads();
#pragma unroll
        for (int k = 0; k < 8; k++) {
            int i = k * 256 + t;
            int c = i & 31, w = i >> 5;
            size_t gi = (size_t)w * CC + c0 + c;
            op[gi] = lds[c * LROW + w].x * ORTHO + xp[gi];
        }
        __syncthreads();
    }
}

extern "C" void kernel_launch(void* const* d_in, const int* in_sizes, int n_in,
                              void* d_out, int out_size, void* d_ws, size_t ws_size,
                              hipStream_t stream) {
    const float* x = (const float*)d_in[0];
    const float* w1 = (const float*)d_in[1];
    const float* b1 = (const float*)d_in[2];
    const float* w2 = (const float*)d_in[3];
    const float* b2 = (const float*)d_in[4];
    float* out = (float*)d_out;
    unsigned* buf = (unsigned*)d_ws;  // B*D*H*WR*C u32 = 138.4 MB (L3-resident)

    // 1) rfft along W
    k_rfft_w<<<BB * NDIM * NDIM, 256, 0, stream>>>(x, buf);
    // 2) FFT along H: per (b,d,wr)
    k_fft_axis<-1><<<BB * NDIM * WR, 256, 0, stream>>>(buf, WR, S_Ds, S_WRs, S_Hs);
    // 3) FFT along D: per (b,h,wr)
    k_fft_axis<-1><<<BB * NDIM * WR, 256, 0, stream>>>(buf, NDIM * WR, S_Bs, S_WRs, S_Ds);
    // 4) block-diagonal complex MLP + softshrink via MFMA (64 points per CTA)
    k_mlp<<<(BB * NDIM * NDIM * WR) / 64, 256, 0, stream>>>(buf, w1, b1, w2, b2);
    // 5) inverse FFT along D
    k_fft_axis<1><<<BB * NDIM * WR, 256, 0, stream>>>(buf, NDIM * WR, S_Bs, S_WRs, S_Ds);
    // 6) inverse FFT along H
    k_fft_axis<1><<<BB * NDIM * WR, 256, 0, stream>>>(buf, WR, S_Ds, S_WRs, S_Hs);
    // 7) irfft along W + residual
    k_irfft_w<<<BB * NDIM * NDIM, 256, 0, stream>>>(buf, x, out);
}

// Round 7
// 559.810 us; speedup vs baseline: 2.6013x; 1.7026x over previous
//
#include <hip/hip_runtime.h>
#include <math.h>

// Problem constants
#define BB 2
#define NDIM 64      // D = H = W = 64
#define CC 128       // channels
#define WR 33        // rfft bins along W
#define NBLK 8
#define BSZ 16

static constexpr float LAM = 0.01f;            // softshrink lambda
static constexpr float ORTHO = 1.0f / 512.0f;  // 1/sqrt(64^3)
static constexpr float TWO_PI_64 = 6.28318530717958647692f / 64.0f;

// LDS row stride (in float2) for one 64-elem transform: pad 64 -> 66.
#define LROW 66

// Spectrum element strides (uint32 units), layout (b, d, h, wr, c)
#define S_WRs 128L
#define S_Hs 4224L      // 33*128
#define S_Ds 270336L    // 64*4224
#define S_Bs 17301504L  // 64*270336

typedef short bf16x8 __attribute__((ext_vector_type(8)));
typedef float f32x4v __attribute__((ext_vector_type(4)));

__device__ inline float2 cmulf(float2 a, float2 b) {
    return make_float2(a.x * b.x - a.y * b.y, a.x * b.y + a.y * b.x);
}
__device__ inline float2 cadd(float2 a, float2 b) { return make_float2(a.x + b.x, a.y + b.y); }
__device__ inline float2 csub(float2 a, float2 b) { return make_float2(a.x - b.x, a.y - b.y); }

// bf16 pack/unpack (RNE). first elem in low 16, second in high 16.
__device__ inline unsigned pack_c(float2 v) {
    unsigned ua = __float_as_uint(v.x), ub = __float_as_uint(v.y);
    ua += 0x7fffu + ((ua >> 16) & 1u);
    ub += 0x7fffu + ((ub >> 16) & 1u);
    return (ua >> 16) | (ub & 0xffff0000u);
}
__device__ inline float2 unpack_c(unsigned u) {
    return make_float2(__uint_as_float(u << 16), __uint_as_float(u & 0xffff0000u));
}

// Fast 8-point DFT, radix-2 DIT (two 4-pt FFTs + W8 combine).
// DIR = -1 forward (e^{-i}), +1 inverse. ~56 real ops (vs ~336 naive).
// Verified against deltas at n=1,2,3,4 both directions.
template <int DIR>
__device__ inline float2 jmul(float2 z) {  // DIR*i * z : fwd -> -i*z, inv -> +i*z
    return (DIR < 0) ? make_float2(z.y, -z.x) : make_float2(-z.y, z.x);
}
template <int DIR>
__device__ inline void dft8(const float2 v[8], float2 y[8]) {
    const float s = 0.70710678118654752440f;
    // even 4-pt FFT on v0,v2,v4,v6
    float2 a0 = cadd(v[0], v[4]), a1 = csub(v[0], v[4]);
    float2 a2 = cadd(v[2], v[6]), a3 = csub(v[2], v[6]);
    float2 A0 = cadd(a0, a2), A2 = csub(a0, a2);
    float2 tj = jmul<DIR>(a3);
    float2 A1 = cadd(a1, tj), A3 = csub(a1, tj);
    // odd 4-pt FFT on v1,v3,v5,v7
    float2 b0 = cadd(v[1], v[5]), b1 = csub(v[1], v[5]);
    float2 b2 = cadd(v[3], v[7]), b3 = csub(v[3], v[7]);
    float2 B0 = cadd(b0, b2), B2 = csub(b0, b2);
    float2 uj = jmul<DIR>(b3);
    float2 B1 = cadd(b1, uj), B3 = csub(b1, uj);
    // W8^k * B_k
    float2 W1B1 = (DIR < 0) ? make_float2(s * (B1.x + B1.y), s * (B1.y - B1.x))
                            : make_float2(s * (B1.x - B1.y), s * (B1.x + B1.y));
    float2 W2B2 = jmul<DIR>(B2);
    float2 W3B3 = (DIR < 0) ? make_float2(s * (B3.y - B3.x), -s * (B3.x + B3.y))
                            : make_float2(-s * (B3.x + B3.y), s * (B3.x - B3.y));
    y[0] = cadd(A0, B0);   y[4] = csub(A0, B0);
    y[1] = cadd(A1, W1B1); y[5] = csub(A1, W1B1);
    y[2] = cadd(A2, W2B2); y[6] = csub(A2, W2B2);
    y[3] = cadd(A3, W3B3); y[7] = csub(A3, W3B3);
}

// Per-thread twiddles for its p = t&7: tw[k1-1] = (cos, sin)(+2*pi*p*k1/64)
__device__ inline void make_tw(int p, float2 tw[7]) {
#pragma unroll
    for (int k1 = 1; k1 < 8; k1++) {
        float ang = TWO_PI_64 * (float)(p * k1);
        float sn, cs;
        __sincosf(ang, &sn, &cs);
        tw[k1 - 1] = make_float2(cs, sn);
    }
}

// 64-pt FFT on 64 contiguous float2 in LDS (base), cooperatively by 8 threads
// p = 0..7 (lanes 8r..8r+7 of ONE wave -> wave-synchronous, no block barriers:
// DS ops from one wave execute in order; wave_barrier() stops compiler motion).
// Natural order in, natural order out.
template <int DIR>
__device__ inline void fft64_lds(float2* base, int p, const float2 tw[7]) {
    float2 v[8], a[8];
#pragma unroll
    for (int n1 = 0; n1 < 8; n1++) v[n1] = base[8 * n1 + p];
    dft8<DIR>(v, a);
#pragma unroll
    for (int k1 = 1; k1 < 8; k1++) {
        float2 w = make_float2(tw[k1 - 1].x, (float)DIR * tw[k1 - 1].y);
        a[k1] = cmulf(a[k1], w);
    }
#pragma unroll
    for (int k1 = 0; k1 < 8; k1++) base[8 * k1 + p] = a[k1];
    __builtin_amdgcn_wave_barrier();  // cross-lane exchange within the wave
    float2 u[8], y[8];
#pragma unroll
    for (int n2 = 0; n2 < 8; n2++) u[n2] = base[8 * p + n2];
    dft8<DIR>(u, y);
    __builtin_amdgcn_wave_barrier();  // all group reads precede overwrites
#pragma unroll
    for (int k2 = 0; k2 < 8; k2++) base[8 * k2 + p] = y[k2];  // holds X[p + 8*k2]
}

// ---------------- Pass 1: rfft along W. x f32 -> buf (b,d,h,wr,c) packed bf16
__global__ __launch_bounds__(256) void k_rfft_w(const float* __restrict__ x,
                                                unsigned* __restrict__ buf) {
    __shared__ float2 lds[32 * LROW];
    const int t = threadIdx.x;
    const size_t bdh = blockIdx.x;
    const float* xp = x + bdh * (size_t)(NDIM * CC);
    unsigned* op = buf + bdh * (size_t)(WR * CC);
    float2 tw[7];
    make_tw(t & 7, tw);
    for (int chunk = 0; chunk < 4; chunk++) {
        const int c0 = chunk * 32;
#pragma unroll
        for (int k = 0; k < 8; k++) {
            int i = k * 256 + t;
            int c = i & 31, w = i >> 5;
            float vv = xp[(size_t)w * CC + c0 + c] * ORTHO;
            lds[c * LROW + w] = make_float2(vv, 0.f);
        }
        __syncthreads();
        fft64_lds<-1>(&lds[(t >> 3) * LROW], t & 7, tw);
        __syncthreads();
        for (int i = t; i < WR * 32; i += 256) {
            int c = i & 31, kk = i >> 5;
            op[(size_t)kk * CC + c0 + c] = pack_c(lds[c * LROW + kk]);
        }
        __syncthreads();
    }
}

// ---------------- Passes 2,3,5,6: in-place complex FFT along a strided axis.
template <int DIR>
__global__ __launch_bounds__(256) void k_fft_axis(unsigned* __restrict__ buf, int outerB,
                                                  long sA, long sB, long sAxis) {
    __shared__ float2 lds[32 * LROW];
    const int t = threadIdx.x;
    const long a = blockIdx.x / outerB;
    const long ob = blockIdx.x % outerB;
    unsigned* p0 = buf + a * sA + ob * sB;
    float2 tw[7];
    make_tw(t & 7, tw);
    for (int chunk = 0; chunk < 4; chunk++) {
        const int c0 = chunk * 32;
#pragma unroll
        for (int k = 0; k < 8; k++) {
            int i = k * 256 + t;
            int c = i & 31, n = i >> 5;
            lds[c * LROW + n] = unpack_c(p0[(long)n * sAxis + c0 + c]);
        }
        __syncthreads();
        fft64_lds<DIR>(&lds[(t >> 3) * LROW], t & 7, tw);
        __syncthreads();
#pragma unroll
        for (int k = 0; k < 8; k++) {
            int i = k * 256 + t;
            int c = i & 31, n = i >> 5;
            p0[(long)n * sAxis + c0 + c] = pack_c(lds[c * LROW + n]);
        }
        __syncthreads();
    }
}

// ---------------- Pass 4: block-diag complex MLP + softshrink, in place, via MFMA.
// Complex GEMM as real: [o_r|o_i] = [x_r|x_i] * [[Wr, Wi], [-Wi, Wr]].
// CTA = 256 threads = 4 waves; wave = 16 points x all 8 blocks.
// A/B frags both built by us with the SAME k-map (k = (lane>>4)*8 + elem), so
// any HW k-permutation cancels. C/D layout (col=lane&15, row=(lane>>4)*4+reg)
// is the HW-verified mapping.
__global__ __launch_bounds__(256) void k_mlp(unsigned* __restrict__ buf,
                                             const float* __restrict__ w1,
                                             const float* __restrict__ b1,
                                             const float* __restrict__ w2,
                                             const float* __restrict__ b2) {
    __shared__ uint4 WF[2048];          // [blk][layer][half][lane] -> 32 KB
    __shared__ float BIAS[512];         // b1r|b1i|b2r|b2i, 128 each
    __shared__ unsigned SHUF[4 * 272];  // per-wave 16 x (pitch 17)
    const int t = threadIdx.x;

    // Build B-fragments (bf16) once per CTA.
    for (int widx = t; widx < 2048; widx += 256) {
        const int lane = widx & 63;
        const int half = (widx >> 6) & 1;   // 0: real-out cols, 1: imag-out cols
        const float* ws = (widx & 128) ? w2 : w1;
        const int blk = widx >> 8;
        const int n = lane & 15;
        const int kc = lane >> 4;
        unsigned wrd[4];
#pragma unroll
        for (int j2 = 0; j2 < 4; j2++) {
            float v[2];
#pragma unroll
            for (int e = 0; e < 2; e++) {
                const int k = kc * 8 + j2 * 2 + e;
                float val;
                if (k < 16)
                    val = half ? ws[2048 + blk * 256 + k * 16 + n]
                               : ws[blk * 256 + k * 16 + n];
                else
                    val = half ? ws[blk * 256 + (k - 16) * 16 + n]
                               : -ws[2048 + blk * 256 + (k - 16) * 16 + n];
                v[e] = val;
            }
            wrd[j2] = pack_c(make_float2(v[0], v[1]));
        }
        WF[widx] = make_uint4(wrd[0], wrd[1], wrd[2], wrd[3]);
    }
    BIAS[t] = b1[t];        // t < 256 always
    BIAS[256 + t] = b2[t];
    __syncthreads();

    const int wv = t >> 6, l = t & 63;
    const int m = l & 15;          // A row / C col
    const int kc = l >> 4;         // 0..3 k-chunk
    const int c0 = (kc & 1) * 8;   // channel base within block
    const bool imh = kc >= 2;      // lanes 32-63 carry imaginary k-half
    unsigned* shuf = &SHUF[wv * 272];
    unsigned* pbase = buf + (size_t)(blockIdx.x * 64 + wv * 16) * CC;

#pragma unroll 1
    for (int blk = 0; blk < 8; blk++) {
        // ---- A gather (global, packed bf16 pairs)
        const unsigned* arow = pbase + (size_t)m * CC + blk * 16 + c0;
        const uint4 q0 = *(const uint4*)arow;
        const uint4 q1 = *(const uint4*)(arow + 4);
        union { unsigned w[4]; bf16x8 v; } A;
        if (!imh) {
            A.w[0] = (q0.x & 0xffffu) | (q0.y << 16);
            A.w[1] = (q0.z & 0xffffu) | (q0.w << 16);
            A.w[2] = (q1.x & 0xffffu) | (q1.y << 16);
            A.w[3] = (q1.z & 0xffffu) | (q1.w << 16);
        } else {
            A.w[0] = (q0.x >> 16) | (q0.y & 0xffff0000u);
            A.w[1] = (q0.z >> 16) | (q0.w & 0xffff0000u);
            A.w[2] = (q1.x >> 16) | (q1.y & 0xffff0000u);
            A.w[3] = (q1.z >> 16) | (q1.w & 0xffff0000u);
        }
        // ---- layer 1
        union { uint4 q; bf16x8 v; } B1r, B1i, B2r, B2i;
        B1r.q = WF[(blk * 4 + 0) * 64 + l];
        B1i.q = WF[(blk * 4 + 1) * 64 + l];
        f32x4v Dr = {0.f, 0.f, 0.f, 0.f}, Di = {0.f, 0.f, 0.f, 0.f};
        Dr = __builtin_amdgcn_mfma_f32_16x16x32_bf16(A.v, B1r.v, Dr, 0, 0, 0);
        Di = __builtin_amdgcn_mfma_f32_16x16x32_bf16(A.v, B1i.v, Di, 0, 0, 0);
        const float b1r_ = BIAS[blk * 16 + m];
        const float b1i_ = BIAS[128 + blk * 16 + m];
#pragma unroll
        for (int r = 0; r < 4; r++) {
            const float o1r = fmaxf(Dr[r] + b1r_, 0.f);
            const float o1i = fmaxf(Di[r] + b1i_, 0.f);
            shuf[(kc * 4 + r) * 17 + m] = pack_c(make_float2(o1r, o1i));
        }
        // ---- inter-layer redistribution (within-wave; compiler orders LDS deps)
        unsigned s[8];
#pragma unroll
        for (int j = 0; j < 8; j++) s[j] = shuf[m * 17 + c0 + j];
        union { unsigned w[4]; bf16x8 v; } A2;
        if (!imh) {
            A2.w[0] = (s[0] & 0xffffu) | (s[1] << 16);
            A2.w[1] = (s[2] & 0xffffu) | (s[3] << 16);
            A2.w[2] = (s[4] & 0xffffu) | (s[5] << 16);
            A2.w[3] = (s[6] & 0xffffu) | (s[7] << 16);
        } else {
            A2.w[0] = (s[0] >> 16) | (s[1] & 0xffff0000u);
            A2.w[1] = (s[2] >> 16) | (s[3] & 0xffff0000u);
            A2.w[2] = (s[4] >> 16) | (s[5] & 0xffff0000u);
            A2.w[3] = (s[6] >> 16) | (s[7] & 0xffff0000u);
        }
        // ---- layer 2
        B2r.q = WF[(blk * 4 + 2) * 64 + l];
        B2i.q = WF[(blk * 4 + 3) * 64 + l];
        f32x4v Er = {0.f, 0.f, 0.f, 0.f}, Ei = {0.f, 0.f, 0.f, 0.f};
        Er = __builtin_amdgcn_mfma_f32_16x16x32_bf16(A2.v, B2r.v, Er, 0, 0, 0);
        Ei = __builtin_amdgcn_mfma_f32_16x16x32_bf16(A2.v, B2i.v, Ei, 0, 0, 0);
        const float b2r_ = BIAS[256 + blk * 16 + m];
        const float b2i_ = BIAS[384 + blk * 16 + m];
#pragma unroll
        for (int r = 0; r < 4; r++) {
            float sr = Er[r] + b2r_, si = Ei[r] + b2i_;
            sr = (sr > LAM) ? (sr - LAM) : ((sr < -LAM) ? (sr + LAM) : 0.f);
            si = (si > LAM) ? (si - LAM) : ((si < -LAM) ? (si + LAM) : 0.f);
            pbase[(size_t)(kc * 4 + r) * CC + blk * 16 + m] =
                pack_c(make_float2(sr, si));
        }
    }
}

// ---------------- Pass 7: irfft along W + residual.
__global__ __launch_bounds__(256) void k_irfft_w(const unsigned* __restrict__ buf,
                                                 const float* __restrict__ x,
                                                 float* __restrict__ out) {
    __shared__ float2 lds[32 * LROW];
    const int t = threadIdx.x;
    const size_t bdh = blockIdx.x;
    const unsigned* ip = buf + bdh * (size_t)(WR * CC);
    const float* xp = x + bdh * (size_t)(NDIM * CC);
    float* op = out + bdh * (size_t)(NDIM * CC);
    float2 tw[7];
    make_tw(t & 7, tw);
    for (int chunk = 0; chunk < 4; chunk++) {
        const int c0 = chunk * 32;
        for (int i = t; i < WR * 32; i += 256) {
            int c = i & 31, kk = i >> 5;
            lds[c * LROW + kk] = unpack_c(ip[(size_t)kk * CC + c0 + c]);
        }
        __syncthreads();
        // Hermitian fill: X[64-k] = conj(X[k]) for k=1..31
        for (int i = t; i < 31 * 32; i += 256) {
            int c = i & 31, kk = 33 + (i >> 5);
            float2 v = lds[c * LROW + (64 - kk)];
            lds[c * LROW + kk] = make_float2(v.x, -v.y);
        }
        __syncthreads();
        fft64_lds<1>(&lds[(t >> 3) * LROW], t & 7, tw);
        __syncthreads();
#pragma unroll
        for (int k = 0; k < 8; k++) {
            int i = k * 256 + t;
            int c = i & 31, w = i >> 5;
            size_t gi = (size_t)w * CC + c0 + c;
            op[gi] = lds[c * LROW + w].x * ORTHO + xp[gi];
        }
        __syncthreads();
    }
}

extern "C" void kernel_launch(void* const* d_in, const int* in_sizes, int n_in,
                              void* d_out, int out_size, void* d_ws, size_t ws_size,
                              hipStream_t stream) {
    const float* x = (const float*)d_in[0];
    const float* w1 = (const float*)d_in[1];
    const float* b1 = (const float*)d_in[2];
    const float* w2 = (const float*)d_in[3];
    const float* b2 = (const float*)d_in[4];
    float* out = (float*)d_out;
    unsigned* buf = (unsigned*)d_ws;  // B*D*H*WR*C u32 = 138.4 MB (L3-resident)

    // 1) rfft along W
    k_rfft_w<<<BB * NDIM * NDIM, 256, 0, stream>>>(x, buf);
    // 2) FFT along H: per (b,d,wr)
    k_fft_axis<-1><<<BB * NDIM * WR, 256, 0, stream>>>(buf, WR, S_Ds, S_WRs, S_Hs);
    // 3) FFT along D: per (b,h,wr)
    k_fft_axis<-1><<<BB * NDIM * WR, 256, 0, stream>>>(buf, NDIM * WR, S_Bs, S_WRs, S_Ds);
    // 4) block-diagonal complex MLP + softshrink via MFMA (64 points per CTA)
    k_mlp<<<(BB * NDIM * NDIM * WR) / 64, 256, 0, stream>>>(buf, w1, b1, w2, b2);
    // 5) inverse FFT along D
    k_fft_axis<1><<<BB * NDIM * WR, 256, 0, stream>>>(buf, NDIM * WR, S_Bs, S_WRs, S_Ds);
    // 6) inverse FFT along H
    k_fft_axis<1><<<BB * NDIM * WR, 256, 0, stream>>>(buf, WR, S_Ds, S_WRs, S_Hs);
    // 7) irfft along W + residual
    k_irfft_w<<<BB * NDIM * NDIM, 256, 0, stream>>>(buf, x, out);
}

// Round 8
// 530.099 us; speedup vs baseline: 2.7471x; 1.0560x over previous
//
#include <hip/hip_runtime.h>
#include <math.h>

// Problem constants
#define BB 2
#define NDIM 64      // D = H = W = 64
#define CC 128       // channels
#define WR 33        // rfft bins along W
#define NBLK 8
#define BSZ 16

static constexpr float LAM = 0.01f;            // softshrink lambda
static constexpr float ORTHO = 1.0f / 512.0f;  // 1/sqrt(64^3)
static constexpr float TWO_PI_64 = 6.28318530717958647692f / 64.0f;

// LDS row stride (in float2) for one 64-elem transform: pad 64 -> 66.
#define LROW 66
// Fused-kernel LDS pitch (u32) for [d][c] plane: 130 -> FFT cols ~2-4 way,
// MLP rows conflict-free, rows 8B-aligned (520 B).
#define DP 130

// Spectrum element strides (uint32 units), layout (b, d, h, wr, c)
#define S_WRs 128L
#define S_Hs 4224L      // 33*128
#define S_Ds 270336L    // 64*4224
#define S_Bs 17301504L  // 64*270336

typedef short bf16x8 __attribute__((ext_vector_type(8)));
typedef float f32x4v __attribute__((ext_vector_type(4)));

__device__ inline float2 cmulf(float2 a, float2 b) {
    return make_float2(a.x * b.x - a.y * b.y, a.x * b.y + a.y * b.x);
}
__device__ inline float2 cadd(float2 a, float2 b) { return make_float2(a.x + b.x, a.y + b.y); }
__device__ inline float2 csub(float2 a, float2 b) { return make_float2(a.x - b.x, a.y - b.y); }

// bf16 pack/unpack (RNE). first elem in low 16, second in high 16.
__device__ inline unsigned pack_c(float2 v) {
    unsigned ua = __float_as_uint(v.x), ub = __float_as_uint(v.y);
    ua += 0x7fffu + ((ua >> 16) & 1u);
    ub += 0x7fffu + ((ub >> 16) & 1u);
    return (ua >> 16) | (ub & 0xffff0000u);
}
__device__ inline float2 unpack_c(unsigned u) {
    return make_float2(__uint_as_float(u << 16), __uint_as_float(u & 0xffff0000u));
}

// Fast 8-point DFT, radix-2 DIT. DIR = -1 forward, +1 inverse. ~56 real ops.
template <int DIR>
__device__ inline float2 jmul(float2 z) {  // DIR*i * z
    return (DIR < 0) ? make_float2(z.y, -z.x) : make_float2(-z.y, z.x);
}
template <int DIR>
__device__ inline void dft8(const float2 v[8], float2 y[8]) {
    const float s = 0.70710678118654752440f;
    float2 a0 = cadd(v[0], v[4]), a1 = csub(v[0], v[4]);
    float2 a2 = cadd(v[2], v[6]), a3 = csub(v[2], v[6]);
    float2 A0 = cadd(a0, a2), A2 = csub(a0, a2);
    float2 tj = jmul<DIR>(a3);
    float2 A1 = cadd(a1, tj), A3 = csub(a1, tj);
    float2 b0 = cadd(v[1], v[5]), b1 = csub(v[1], v[5]);
    float2 b2 = cadd(v[3], v[7]), b3 = csub(v[3], v[7]);
    float2 B0 = cadd(b0, b2), B2 = csub(b0, b2);
    float2 uj = jmul<DIR>(b3);
    float2 B1 = cadd(b1, uj), B3 = csub(b1, uj);
    float2 W1B1 = (DIR < 0) ? make_float2(s * (B1.x + B1.y), s * (B1.y - B1.x))
                            : make_float2(s * (B1.x - B1.y), s * (B1.x + B1.y));
    float2 W2B2 = jmul<DIR>(B2);
    float2 W3B3 = (DIR < 0) ? make_float2(s * (B3.y - B3.x), -s * (B3.x + B3.y))
                            : make_float2(-s * (B3.x + B3.y), s * (B3.x - B3.y));
    y[0] = cadd(A0, B0);   y[4] = csub(A0, B0);
    y[1] = cadd(A1, W1B1); y[5] = csub(A1, W1B1);
    y[2] = cadd(A2, W2B2); y[6] = csub(A2, W2B2);
    y[3] = cadd(A3, W3B3); y[7] = csub(A3, W3B3);
}

// Per-thread twiddles for its p = t&7: tw[k1-1] = (cos, sin)(+2*pi*p*k1/64)
__device__ inline void make_tw(int p, float2 tw[7]) {
#pragma unroll
    for (int k1 = 1; k1 < 8; k1++) {
        float ang = TWO_PI_64 * (float)(p * k1);
        float sn, cs;
        __sincosf(ang, &sn, &cs);
        tw[k1 - 1] = make_float2(cs, sn);
    }
}

// 64-pt FFT on 64 contiguous float2 in LDS, cooperatively by 8 threads p=0..7
// (lanes 8r..8r+7 of ONE wave: wave-synchronous, no block barriers).
// Natural order in, natural order out (X[p+8k2] stored at index 8k2+p = p+8k2).
template <int DIR>
__device__ inline void fft64_lds(float2* base, int p, const float2 tw[7]) {
    float2 v[8], a[8];
#pragma unroll
    for (int n1 = 0; n1 < 8; n1++) v[n1] = base[8 * n1 + p];
    dft8<DIR>(v, a);
#pragma unroll
    for (int k1 = 1; k1 < 8; k1++) {
        float2 w = make_float2(tw[k1 - 1].x, (float)DIR * tw[k1 - 1].y);
        a[k1] = cmulf(a[k1], w);
    }
#pragma unroll
    for (int k1 = 0; k1 < 8; k1++) base[8 * k1 + p] = a[k1];
    __builtin_amdgcn_wave_barrier();
    float2 u[8], y[8];
#pragma unroll
    for (int n2 = 0; n2 < 8; n2++) u[n2] = base[8 * p + n2];
    dft8<DIR>(u, y);
    __builtin_amdgcn_wave_barrier();
#pragma unroll
    for (int k2 = 0; k2 < 8; k2++) base[8 * k2 + p] = y[k2];
}

// Packed-bf16 strided variant for the fused D-axis kernel: element i at
// col[i*DP] (u32 packed re/im). One extra bf16 rounding at the stage boundary.
template <int DIR>
__device__ inline void pfft64(unsigned* col, int p, const float2 tw[7]) {
    float2 v[8], a[8];
#pragma unroll
    for (int n1 = 0; n1 < 8; n1++) v[n1] = unpack_c(col[(8 * n1 + p) * DP]);
    dft8<DIR>(v, a);
#pragma unroll
    for (int k1 = 1; k1 < 8; k1++) {
        float2 w = make_float2(tw[k1 - 1].x, (float)DIR * tw[k1 - 1].y);
        a[k1] = cmulf(a[k1], w);
    }
#pragma unroll
    for (int k1 = 0; k1 < 8; k1++) col[(8 * k1 + p) * DP] = pack_c(a[k1]);
    __builtin_amdgcn_wave_barrier();
    float2 u[8], y[8];
#pragma unroll
    for (int n2 = 0; n2 < 8; n2++) u[n2] = unpack_c(col[(8 * p + n2) * DP]);
    dft8<DIR>(u, y);
    __builtin_amdgcn_wave_barrier();
#pragma unroll
    for (int k2 = 0; k2 < 8; k2++) col[(8 * k2 + p) * DP] = pack_c(y[k2]);
}

// ---------------- Pass 1: rfft along W, two real channels packed per complex
// FFT. x f32 -> buf (b,d,h,wr,c) packed bf16.
__global__ __launch_bounds__(256) void k_rfft_w(const float* __restrict__ x,
                                                unsigned* __restrict__ buf) {
    __shared__ float2 lds[32 * LROW];
    const int t = threadIdx.x;
    const size_t bdh = blockIdx.x;
    const float* xp = x + bdh * (size_t)(NDIM * CC);
    unsigned* op = buf + bdh * (size_t)(WR * CC);
    float2 tw[7];
    make_tw(t & 7, tw);
    for (int chunk = 0; chunk < 2; chunk++) {
        const int c0 = chunk * 64;  // 32 channel-pairs per chunk
#pragma unroll
        for (int k8 = 0; k8 < 8; k8++) {
            int idx = k8 * 256 + t;
            int p = idx & 31, w = idx >> 5;
            float2 v = *(const float2*)&xp[(size_t)w * CC + c0 + 2 * p];
            lds[p * LROW + w] = make_float2(v.x * ORTHO, v.y * ORTHO);
        }
        __syncthreads();
        fft64_lds<-1>(&lds[(t >> 3) * LROW], t & 7, tw);
        __syncthreads();
        // untangle: Xa = (Z[k]+conj(Z[m]))/2, Xb = -i(Z[k]-conj(Z[m]))/2, m=64-k
        for (int i = t; i < WR * 32; i += 256) {
            int p = i & 31, k = i >> 5;
            int m = (64 - k) & 63;
            float2 Z1 = lds[p * LROW + k];
            float2 Z2 = lds[p * LROW + m];
            float2 Xa = make_float2(0.5f * (Z1.x + Z2.x), 0.5f * (Z1.y - Z2.y));
            float2 Xb = make_float2(0.5f * (Z1.y + Z2.y), 0.5f * (Z2.x - Z1.x));
            uint2 u = make_uint2(pack_c(Xa), pack_c(Xb));
            *(uint2*)&op[(size_t)k * CC + c0 + 2 * p] = u;
        }
        __syncthreads();
    }
}

// ---------------- Passes 2,4: in-place complex FFT along H (strided axis).
template <int DIR>
__global__ __launch_bounds__(256) void k_fft_axis(unsigned* __restrict__ buf, int outerB,
                                                  long sA, long sB, long sAxis) {
    __shared__ float2 lds[32 * LROW];
    const int t = threadIdx.x;
    const long a = blockIdx.x / outerB;
    const long ob = blockIdx.x % outerB;
    unsigned* p0 = buf + a * sA + ob * sB;
    float2 tw[7];
    make_tw(t & 7, tw);
    for (int chunk = 0; chunk < 4; chunk++) {
        const int c0 = chunk * 32;
#pragma unroll
        for (int k = 0; k < 8; k++) {
            int i = k * 256 + t;
            int c = i & 31, n = i >> 5;
            lds[c * LROW + n] = unpack_c(p0[(long)n * sAxis + c0 + c]);
        }
        __syncthreads();
        fft64_lds<DIR>(&lds[(t >> 3) * LROW], t & 7, tw);
        __syncthreads();
#pragma unroll
        for (int k = 0; k < 8; k++) {
            int i = k * 256 + t;
            int c = i & 31, n = i >> 5;
            p0[(long)n * sAxis + c0 + c] = pack_c(lds[c * LROW + n]);
        }
        __syncthreads();
    }
}

// ---------------- Pass 3 (fused): FFT-D -> MFMA block-diag complex MLP +
// softshrink -> iFFT-D, all on an LDS-resident [d=64][c=128] packed tile.
// Complex GEMM as real: [o_r|o_i] = [x_r|x_i] * [[Wr, Wi], [-Wi, Wr]].
// A/B frags share the k-map (k = (lane>>4)*8 + elem); C/D layout is the
// HW-verified (col=lane&15, row=(lane>>4)*4+reg).
__global__ __launch_bounds__(256) void k_dmlp(unsigned* __restrict__ buf,
                                              const float* __restrict__ w1,
                                              const float* __restrict__ b1,
                                              const float* __restrict__ w2,
                                              const float* __restrict__ b2) {
    __shared__ unsigned P[64 * DP];     // 33,280 B  [d][c] packed bf16
    __shared__ uint4 WF[2048];          // 32,768 B  weight fragments
    __shared__ float BIAS[512];         // b1r|b1i|b2r|b2i
    __shared__ unsigned SHUF[4 * 272];  // per-wave 16 x (pitch 17)
    const int t = threadIdx.x;
    int id = blockIdx.x;
    const int wr = id % WR; id /= WR;
    const int h = id % NDIM; id /= NDIM;
    const int b = id;
    unsigned* p0 = buf + (long)b * S_Bs + (long)h * S_Hs + (long)wr * S_WRs;

    // load spectrum tile (uint2-vectorized, coalesced 512B per d-row)
#pragma unroll
    for (int k = 0; k < 16; k++) {
        int idx = k * 256 + t;            // 0..4095 uint2 items
        int d = idx >> 6, c2 = idx & 63;  // c = 2*c2
        *(uint2*)&P[d * DP + 2 * c2] = *(const uint2*)&p0[(long)d * S_Ds + 2 * c2];
    }
    // build weight fragments + biases (independent of P)
    for (int widx = t; widx < 2048; widx += 256) {
        const int lane = widx & 63;
        const int half = (widx >> 6) & 1;
        const float* ws = (widx & 128) ? w2 : w1;
        const int blk = widx >> 8;
        const int n = lane & 15;
        const int kc = lane >> 4;
        unsigned wrd[4];
#pragma unroll
        for (int j2 = 0; j2 < 4; j2++) {
            float v[2];
#pragma unroll
            for (int e = 0; e < 2; e++) {
                const int k = kc * 8 + j2 * 2 + e;
                float val;
                if (k < 16)
                    val = half ? ws[2048 + blk * 256 + k * 16 + n]
                               : ws[blk * 256 + k * 16 + n];
                else
                    val = half ? ws[blk * 256 + (k - 16) * 16 + n]
                               : -ws[2048 + blk * 256 + (k - 16) * 16 + n];
                v[e] = val;
            }
            wrd[j2] = pack_c(make_float2(v[0], v[1]));
        }
        WF[widx] = make_uint4(wrd[0], wrd[1], wrd[2], wrd[3]);
    }
    BIAS[t] = b1[t];
    BIAS[256 + t] = b2[t];
    float2 tw[7];
    make_tw(t & 7, tw);
    __syncthreads();

    // forward FFT along d: 128 columns, 32 groups of 8 threads, 4 iterations
#pragma unroll 1
    for (int it = 0; it < 4; it++) pfft64<-1>(&P[(t >> 3) + 32 * it], t & 7, tw);
    __syncthreads();

    // MFMA MLP on 64 points x 8 blocks; wave wv owns point rows wv*16..+15
    {
        const int wv = t >> 6, l = t & 63;
        const int m = l & 15;
        const int kc = l >> 4;
        const int c0m = (kc & 1) * 8;
        const bool imh = kc >= 2;
        unsigned* shuf = &SHUF[wv * 272];
        const int prow = wv * 16;

#pragma unroll 1
        for (int blk = 0; blk < 8; blk++) {
            const unsigned* arow = &P[(prow + m) * DP + blk * 16 + c0m];
            const uint2 e0 = *(const uint2*)(arow + 0);
            const uint2 e1 = *(const uint2*)(arow + 2);
            const uint2 e2 = *(const uint2*)(arow + 4);
            const uint2 e3 = *(const uint2*)(arow + 6);
            union { unsigned w[4]; bf16x8 v; } A;
            if (!imh) {
                A.w[0] = (e0.x & 0xffffu) | (e0.y << 16);
                A.w[1] = (e1.x & 0xffffu) | (e1.y << 16);
                A.w[2] = (e2.x & 0xffffu) | (e2.y << 16);
                A.w[3] = (e3.x & 0xffffu) | (e3.y << 16);
            } else {
                A.w[0] = (e0.x >> 16) | (e0.y & 0xffff0000u);
                A.w[1] = (e1.x >> 16) | (e1.y & 0xffff0000u);
                A.w[2] = (e2.x >> 16) | (e2.y & 0xffff0000u);
                A.w[3] = (e3.x >> 16) | (e3.y & 0xffff0000u);
            }
            union { uint4 q; bf16x8 v; } B1r, B1i, B2r, B2i;
            B1r.q = WF[(blk * 4 + 0) * 64 + l];
            B1i.q = WF[(blk * 4 + 1) * 64 + l];
            f32x4v Dr = {0.f, 0.f, 0.f, 0.f}, Di = {0.f, 0.f, 0.f, 0.f};
            Dr = __builtin_amdgcn_mfma_f32_16x16x32_bf16(A.v, B1r.v, Dr, 0, 0, 0);
            Di = __builtin_amdgcn_mfma_f32_16x16x32_bf16(A.v, B1i.v, Di, 0, 0, 0);
            const float b1r_ = BIAS[blk * 16 + m];
            const float b1i_ = BIAS[128 + blk * 16 + m];
#pragma unroll
            for (int r = 0; r < 4; r++) {
                const float o1r = fmaxf(Dr[r] + b1r_, 0.f);
                const float o1i = fmaxf(Di[r] + b1i_, 0.f);
                shuf[(kc * 4 + r) * 17 + m] = pack_c(make_float2(o1r, o1i));
            }
            unsigned s[8];
#pragma unroll
            for (int j = 0; j < 8; j++) s[j] = shuf[m * 17 + c0m + j];
            union { unsigned w[4]; bf16x8 v; } A2;
            if (!imh) {
                A2.w[0] = (s[0] & 0xffffu) | (s[1] << 16);
                A2.w[1] = (s[2] & 0xffffu) | (s[3] << 16);
                A2.w[2] = (s[4] & 0xffffu) | (s[5] << 16);
                A2.w[3] = (s[6] & 0xffffu) | (s[7] << 16);
            } else {
                A2.w[0] = (s[0] >> 16) | (s[1] & 0xffff0000u);
                A2.w[1] = (s[2] >> 16) | (s[3] & 0xffff0000u);
                A2.w[2] = (s[4] >> 16) | (s[5] & 0xffff0000u);
                A2.w[3] = (s[6] >> 16) | (s[7] & 0xffff0000u);
            }
            B2r.q = WF[(blk * 4 + 2) * 64 + l];
            B2i.q = WF[(blk * 4 + 3) * 64 + l];
            f32x4v Er = {0.f, 0.f, 0.f, 0.f}, Ei = {0.f, 0.f, 0.f, 0.f};
            Er = __builtin_amdgcn_mfma_f32_16x16x32_bf16(A2.v, B2r.v, Er, 0, 0, 0);
            Ei = __builtin_amdgcn_mfma_f32_16x16x32_bf16(A2.v, B2i.v, Ei, 0, 0, 0);
            const float b2r_ = BIAS[256 + blk * 16 + m];
            const float b2i_ = BIAS[384 + blk * 16 + m];
#pragma unroll
            for (int r = 0; r < 4; r++) {
                float sr = Er[r] + b2r_, si = Ei[r] + b2i_;
                sr = (sr > LAM) ? (sr - LAM) : ((sr < -LAM) ? (sr + LAM) : 0.f);
                si = (si > LAM) ? (si - LAM) : ((si < -LAM) ? (si + LAM) : 0.f);
                P[(prow + kc * 4 + r) * DP + blk * 16 + m] =
                    pack_c(make_float2(sr, si));
            }
        }
    }
    __syncthreads();

    // inverse FFT along d, then store back
#pragma unroll 1
    for (int it = 0; it < 4; it++) pfft64<1>(&P[(t >> 3) + 32 * it], t & 7, tw);
    __syncthreads();
#pragma unroll
    for (int k = 0; k < 16; k++) {
        int idx = k * 256 + t;
        int d = idx >> 6, c2 = idx & 63;
        *(uint2*)&p0[(long)d * S_Ds + 2 * c2] = *(const uint2*)&P[d * DP + 2 * c2];
    }
}

// ---------------- Pass 5: irfft along W + residual, two channels per inverse
// complex FFT (Z[k] = Xa[k] + i*Xb[k], Hermitian-extended; DC/Nyq imag zeroed
// to match C2R semantics).
__global__ __launch_bounds__(256) void k_irfft_w(const unsigned* __restrict__ buf,
                                                 const float* __restrict__ x,
                                                 float* __restrict__ out) {
    __shared__ float2 lds[32 * LROW];
    const int t = threadIdx.x;
    const size_t bdh = blockIdx.x;
    const unsigned* ip = buf + bdh * (size_t)(WR * CC);
    const float* xp = x + bdh * (size_t)(NDIM * CC);
    float* op = out + bdh * (size_t)(NDIM * CC);
    float2 tw[7];
    make_tw(t & 7, tw);
    for (int chunk = 0; chunk < 2; chunk++) {
        const int c0 = chunk * 64;
        for (int i = t; i < WR * 32; i += 256) {
            int p = i & 31, k = i >> 5;
            uint2 u = *(const uint2*)&ip[(size_t)k * CC + c0 + 2 * p];
            float2 Xa = unpack_c(u.x);
            float2 Xb = unpack_c(u.y);
            if (k == 0 || k == 32) { Xa.y = 0.f; Xb.y = 0.f; }
            lds[p * LROW + k] = make_float2(Xa.x - Xb.y, Xa.y + Xb.x);
            if (k >= 1 && k <= 31)
                lds[p * LROW + (64 - k)] = make_float2(Xa.x + Xb.y, Xb.x - Xa.y);
        }
        __syncthreads();
        fft64_lds<1>(&lds[(t >> 3) * LROW], t & 7, tw);
        __syncthreads();
#pragma unroll
        for (int k8 = 0; k8 < 8; k8++) {
            int idx = k8 * 256 + t;
            int p = idx & 31, w = idx >> 5;
            float2 z = lds[p * LROW + w];
            size_t gi = (size_t)w * CC + c0 + 2 * p;
            float2 xv = *(const float2*)&xp[gi];
            float2 o = make_float2(z.x * ORTHO + xv.x, z.y * ORTHO + xv.y);
            *(float2*)&op[gi] = o;
        }
        __syncthreads();
    }
}

extern "C" void kernel_launch(void* const* d_in, const int* in_sizes, int n_in,
                              void* d_out, int out_size, void* d_ws, size_t ws_size,
                              hipStream_t stream) {
    const float* x = (const float*)d_in[0];
    const float* w1 = (const float*)d_in[1];
    const float* b1 = (const float*)d_in[2];
    const float* w2 = (const float*)d_in[3];
    const float* b2 = (const float*)d_in[4];
    float* out = (float*)d_out;
    unsigned* buf = (unsigned*)d_ws;  // B*D*H*WR*C u32 = 138.4 MB (L3-resident)

    // 1) rfft along W (channel-pair packed)
    k_rfft_w<<<BB * NDIM * NDIM, 256, 0, stream>>>(x, buf);
    // 2) FFT along H
    k_fft_axis<-1><<<BB * NDIM * WR, 256, 0, stream>>>(buf, WR, S_Ds, S_WRs, S_Hs);
    // 3) fused FFT-D -> MFMA MLP + softshrink -> iFFT-D
    k_dmlp<<<BB * NDIM * WR, 256, 0, stream>>>(buf, w1, b1, w2, b2);
    // 4) inverse FFT along H
    k_fft_axis<1><<<BB * NDIM * WR, 256, 0, stream>>>(buf, WR, S_Ds, S_WRs, S_Hs);
    // 5) irfft along W + residual (channel-pair packed)
    k_irfft_w<<<BB * NDIM * NDIM, 256, 0, stream>>>(buf, x, out);
}

// Round 9
// 498.625 us; speedup vs baseline: 2.9205x; 1.0631x over previous
//
#include <hip/hip_runtime.h>
#include <math.h>

// Problem constants
#define BB 2
#define NDIM 64      // D = H = W = 64
#define CC 128       // channels
#define WR 33        // rfft bins along W
#define NBLK 8
#define BSZ 16

static constexpr float LAM = 0.01f;            // softshrink lambda
static constexpr float ORTHO = 1.0f / 512.0f;  // 1/sqrt(64^3)
static constexpr float TWO_PI_64 = 6.28318530717958647692f / 64.0f;

// LDS row stride (in float2) for one 64-elem transform: pad 64 -> 66.
#define LROW 66

// Spectrum element strides (uint32 units), layout (b, d, h, wr, c)
#define S_WRs 128L
#define S_Hs 4224L      // 33*128
#define S_Ds 270336L    // 64*4224
#define S_Bs 17301504L  // 64*270336

typedef short bf16x8 __attribute__((ext_vector_type(8)));
typedef float f32x4v __attribute__((ext_vector_type(4)));

__device__ inline float2 cmulf(float2 a, float2 b) {
    return make_float2(a.x * b.x - a.y * b.y, a.x * b.y + a.y * b.x);
}
__device__ inline float2 cadd(float2 a, float2 b) { return make_float2(a.x + b.x, a.y + b.y); }
__device__ inline float2 csub(float2 a, float2 b) { return make_float2(a.x - b.x, a.y - b.y); }

// bf16 pair pack via HW cvt (RNE): D[15:0]=bf16(x), D[31:16]=bf16(y). 1 VALU op
// vs ~9 for the manual round-to-nearest-even bit sequence.
__device__ inline unsigned pack_c(float2 v) {
    unsigned r;
    asm("v_cvt_pk_bf16_f32 %0, %1, %2" : "=v"(r) : "v"(v.x), "v"(v.y));
    return r;
}
__device__ inline float2 unpack_c(unsigned u) {
    return make_float2(__uint_as_float(u << 16), __uint_as_float(u & 0xffff0000u));
}

// Fast 8-point DFT, radix-2 DIT. DIR = -1 forward, +1 inverse. ~56 real ops.
template <int DIR>
__device__ inline float2 jmul(float2 z) {  // DIR*i * z
    return (DIR < 0) ? make_float2(z.y, -z.x) : make_float2(-z.y, z.x);
}
template <int DIR>
__device__ inline void dft8(const float2 v[8], float2 y[8]) {
    const float s = 0.70710678118654752440f;
    float2 a0 = cadd(v[0], v[4]), a1 = csub(v[0], v[4]);
    float2 a2 = cadd(v[2], v[6]), a3 = csub(v[2], v[6]);
    float2 A0 = cadd(a0, a2), A2 = csub(a0, a2);
    float2 tj = jmul<DIR>(a3);
    float2 A1 = cadd(a1, tj), A3 = csub(a1, tj);
    float2 b0 = cadd(v[1], v[5]), b1 = csub(v[1], v[5]);
    float2 b2 = cadd(v[3], v[7]), b3 = csub(v[3], v[7]);
    float2 B0 = cadd(b0, b2), B2 = csub(b0, b2);
    float2 uj = jmul<DIR>(b3);
    float2 B1 = cadd(b1, uj), B3 = csub(b1, uj);
    float2 W1B1 = (DIR < 0) ? make_float2(s * (B1.x + B1.y), s * (B1.y - B1.x))
                            : make_float2(s * (B1.x - B1.y), s * (B1.x + B1.y));
    float2 W2B2 = jmul<DIR>(B2);
    float2 W3B3 = (DIR < 0) ? make_float2(s * (B3.y - B3.x), -s * (B3.x + B3.y))
                            : make_float2(-s * (B3.x + B3.y), s * (B3.x - B3.y));
    y[0] = cadd(A0, B0);   y[4] = csub(A0, B0);
    y[1] = cadd(A1, W1B1); y[5] = csub(A1, W1B1);
    y[2] = cadd(A2, W2B2); y[6] = csub(A2, W2B2);
    y[3] = cadd(A3, W3B3); y[7] = csub(A3, W3B3);
}

// Per-thread twiddles for its p = t&7: tw[k1-1] = (cos, sin)(+2*pi*p*k1/64)
__device__ inline void make_tw(int p, float2 tw[7]) {
#pragma unroll
    for (int k1 = 1; k1 < 8; k1++) {
        float ang = TWO_PI_64 * (float)(p * k1);
        float sn, cs;
        __sincosf(ang, &sn, &cs);
        tw[k1 - 1] = make_float2(cs, sn);
    }
}

// 64-pt FFT on 64 contiguous float2 in LDS, cooperatively by 8 threads p=0..7
// (lanes 8r..8r+7 of ONE wave: wave-synchronous, no block barriers).
// Natural order in, natural order out.
template <int DIR>
__device__ inline void fft64_lds(float2* base, int p, const float2 tw[7]) {
    float2 v[8], a[8];
#pragma unroll
    for (int n1 = 0; n1 < 8; n1++) v[n1] = base[8 * n1 + p];
    dft8<DIR>(v, a);
#pragma unroll
    for (int k1 = 1; k1 < 8; k1++) {
        float2 w = make_float2(tw[k1 - 1].x, (float)DIR * tw[k1 - 1].y);
        a[k1] = cmulf(a[k1], w);
    }
#pragma unroll
    for (int k1 = 0; k1 < 8; k1++) base[8 * k1 + p] = a[k1];
    __builtin_amdgcn_wave_barrier();
    float2 u[8], y[8];
#pragma unroll
    for (int n2 = 0; n2 < 8; n2++) u[n2] = base[8 * p + n2];
    dft8<DIR>(u, y);
    __builtin_amdgcn_wave_barrier();
#pragma unroll
    for (int k2 = 0; k2 < 8; k2++) base[8 * k2 + p] = y[k2];
}

// ---------------- Pass 1: rfft along W, two real channels packed per complex
// FFT. x f32 -> buf (b,d,h,wr,c) packed bf16.
__global__ __launch_bounds__(256) void k_rfft_w(const float* __restrict__ x,
                                                unsigned* __restrict__ buf) {
    __shared__ float2 lds[32 * LROW];
    const int t = threadIdx.x;
    const size_t bdh = blockIdx.x;
    const float* xp = x + bdh * (size_t)(NDIM * CC);
    unsigned* op = buf + bdh * (size_t)(WR * CC);
    float2 tw[7];
    make_tw(t & 7, tw);
    for (int chunk = 0; chunk < 2; chunk++) {
        const int c0 = chunk * 64;  // 32 channel-pairs per chunk
#pragma unroll
        for (int k8 = 0; k8 < 8; k8++) {
            int idx = k8 * 256 + t;
            int p = idx & 31, w = idx >> 5;
            float2 v = *(const float2*)&xp[(size_t)w * CC + c0 + 2 * p];
            lds[p * LROW + w] = make_float2(v.x * ORTHO, v.y * ORTHO);
        }
        __syncthreads();
        fft64_lds<-1>(&lds[(t >> 3) * LROW], t & 7, tw);
        __syncthreads();
        // untangle: Xa = (Z[k]+conj(Z[m]))/2, Xb = -i(Z[k]-conj(Z[m]))/2, m=64-k
        for (int i = t; i < WR * 32; i += 256) {
            int p = i & 31, k = i >> 5;
            int m = (64 - k) & 63;
            float2 Z1 = lds[p * LROW + k];
            float2 Z2 = lds[p * LROW + m];
            float2 Xa = make_float2(0.5f * (Z1.x + Z2.x), 0.5f * (Z1.y - Z2.y));
            float2 Xb = make_float2(0.5f * (Z1.y + Z2.y), 0.5f * (Z2.x - Z1.x));
            uint2 u = make_uint2(pack_c(Xa), pack_c(Xb));
            *(uint2*)&op[(size_t)k * CC + c0 + 2 * p] = u;
        }
        __syncthreads();
    }
}

// ---------------- Passes 2,3,5,6: in-place complex FFT along a strided axis.
template <int DIR>
__global__ __launch_bounds__(256) void k_fft_axis(unsigned* __restrict__ buf, int outerB,
                                                  long sA, long sB, long sAxis) {
    __shared__ float2 lds[32 * LROW];
    const int t = threadIdx.x;
    const long a = blockIdx.x / outerB;
    const long ob = blockIdx.x % outerB;
    unsigned* p0 = buf + a * sA + ob * sB;
    float2 tw[7];
    make_tw(t & 7, tw);
    for (int chunk = 0; chunk < 4; chunk++) {
        const int c0 = chunk * 32;
#pragma unroll
        for (int k = 0; k < 8; k++) {
            int i = k * 256 + t;
            int c = i & 31, n = i >> 5;
            lds[c * LROW + n] = unpack_c(p0[(long)n * sAxis + c0 + c]);
        }
        __syncthreads();
        fft64_lds<DIR>(&lds[(t >> 3) * LROW], t & 7, tw);
        __syncthreads();
#pragma unroll
        for (int k = 0; k < 8; k++) {
            int i = k * 256 + t;
            int c = i & 31, n = i >> 5;
            p0[(long)n * sAxis + c0 + c] = pack_c(lds[c * LROW + n]);
        }
        __syncthreads();
    }
}

// ---------------- Pass 4: block-diag complex MLP + softshrink, in place, via MFMA.
// Complex GEMM as real: [o_r|o_i] = [x_r|x_i] * [[Wr, Wi], [-Wi, Wr]].
// CTA = 256 threads = 4 waves; wave = 16 points x all 8 blocks.
// A/B frags both built by us with the SAME k-map (k = (lane>>4)*8 + elem), so
// any HW k-permutation cancels. C/D layout (col=lane&15, row=(lane>>4)*4+reg)
// is the HW-verified mapping.
__global__ __launch_bounds__(256) void k_mlp(unsigned* __restrict__ buf,
                                             const float* __restrict__ w1,
                                             const float* __restrict__ b1,
                                             const float* __restrict__ w2,
                                             const float* __restrict__ b2) {
    __shared__ uint4 WF[2048];          // [blk][layer][half][lane] -> 32 KB
    __shared__ float BIAS[512];         // b1r|b1i|b2r|b2i, 128 each
    __shared__ unsigned SHUF[4 * 272];  // per-wave 16 x (pitch 17)
    const int t = threadIdx.x;

    // Build B-fragments (bf16) once per CTA.
    for (int widx = t; widx < 2048; widx += 256) {
        const int lane = widx & 63;
        const int half = (widx >> 6) & 1;   // 0: real-out cols, 1: imag-out cols
        const float* ws = (widx & 128) ? w2 : w1;
        const int blk = widx >> 8;
        const int n = lane & 15;
        const int kc = lane >> 4;
        unsigned wrd[4];
#pragma unroll
        for (int j2 = 0; j2 < 4; j2++) {
            float v[2];
#pragma unroll
            for (int e = 0; e < 2; e++) {
                const int k = kc * 8 + j2 * 2 + e;
                float val;
                if (k < 16)
                    val = half ? ws[2048 + blk * 256 + k * 16 + n]
                               : ws[blk * 256 + k * 16 + n];
                else
                    val = half ? ws[blk * 256 + (k - 16) * 16 + n]
                               : -ws[2048 + blk * 256 + (k - 16) * 16 + n];
                v[e] = val;
            }
            wrd[j2] = pack_c(make_float2(v[0], v[1]));
        }
        WF[widx] = make_uint4(wrd[0], wrd[1], wrd[2], wrd[3]);
    }
    BIAS[t] = b1[t];        // t < 256 always
    BIAS[256 + t] = b2[t];
    __syncthreads();

    const int wv = t >> 6, l = t & 63;
    const int m = l & 15;          // A row / C col
    const int kc = l >> 4;         // 0..3 k-chunk
    const int c0 = (kc & 1) * 8;   // channel base within block
    const bool imh = kc >= 2;      // lanes 32-63 carry imaginary k-half
    unsigned* shuf = &SHUF[wv * 272];
    unsigned* pbase = buf + (size_t)(blockIdx.x * 64 + wv * 16) * CC;

#pragma unroll 1
    for (int blk = 0; blk < 8; blk++) {
        // ---- A gather (global, packed bf16 pairs)
        const unsigned* arow = pbase + (size_t)m * CC + blk * 16 + c0;
        const uint4 q0 = *(const uint4*)arow;
        const uint4 q1 = *(const uint4*)(arow + 4);
        union { unsigned w[4]; bf16x8 v; } A;
        if (!imh) {
            A.w[0] = (q0.x & 0xffffu) | (q0.y << 16);
            A.w[1] = (q0.z & 0xffffu) | (q0.w << 16);
            A.w[2] = (q1.x & 0xffffu) | (q1.y << 16);
            A.w[3] = (q1.z & 0xffffu) | (q1.w << 16);
        } else {
            A.w[0] = (q0.x >> 16) | (q0.y & 0xffff0000u);
            A.w[1] = (q0.z >> 16) | (q0.w & 0xffff0000u);
            A.w[2] = (q1.x >> 16) | (q1.y & 0xffff0000u);
            A.w[3] = (q1.z >> 16) | (q1.w & 0xffff0000u);
        }
        // ---- layer 1
        union { uint4 q; bf16x8 v; } B1r, B1i, B2r, B2i;
        B1r.q = WF[(blk * 4 + 0) * 64 + l];
        B1i.q = WF[(blk * 4 + 1) * 64 + l];
        f32x4v Dr = {0.f, 0.f, 0.f, 0.f}, Di = {0.f, 0.f, 0.f, 0.f};
        Dr = __builtin_amdgcn_mfma_f32_16x16x32_bf16(A.v, B1r.v, Dr, 0, 0, 0);
        Di = __builtin_amdgcn_mfma_f32_16x16x32_bf16(A.v, B1i.v, Di, 0, 0, 0);
        const float b1r_ = BIAS[blk * 16 + m];
        const float b1i_ = BIAS[128 + blk * 16 + m];
#pragma unroll
        for (int r = 0; r < 4; r++) {
            const float o1r = fmaxf(Dr[r] + b1r_, 0.f);
            const float o1i = fmaxf(Di[r] + b1i_, 0.f);
            shuf[(kc * 4 + r) * 17 + m] = pack_c(make_float2(o1r, o1i));
        }
        // ---- inter-layer redistribution (within-wave; compiler orders LDS deps)
        unsigned s[8];
#pragma unroll
        for (int j = 0; j < 8; j++) s[j] = shuf[m * 17 + c0 + j];
        union { unsigned w[4]; bf16x8 v; } A2;
        if (!imh) {
            A2.w[0] = (s[0] & 0xffffu) | (s[1] << 16);
            A2.w[1] = (s[2] & 0xffffu) | (s[3] << 16);
            A2.w[2] = (s[4] & 0xffffu) | (s[5] << 16);
            A2.w[3] = (s[6] & 0xffffu) | (s[7] << 16);
        } else {
            A2.w[0] = (s[0] >> 16) | (s[1] & 0xffff0000u);
            A2.w[1] = (s[2] >> 16) | (s[3] & 0xffff0000u);
            A2.w[2] = (s[4] >> 16) | (s[5] & 0xffff0000u);
            A2.w[3] = (s[6] >> 16) | (s[7] & 0xffff0000u);
        }
        // ---- layer 2
        B2r.q = WF[(blk * 4 + 2) * 64 + l];
        B2i.q = WF[(blk * 4 + 3) * 64 + l];
        f32x4v Er = {0.f, 0.f, 0.f, 0.f}, Ei = {0.f, 0.f, 0.f, 0.f};
        Er = __builtin_amdgcn_mfma_f32_16x16x32_bf16(A2.v, B2r.v, Er, 0, 0, 0);
        Ei = __builtin_amdgcn_mfma_f32_16x16x32_bf16(A2.v, B2i.v, Ei, 0, 0, 0);
        const float b2r_ = BIAS[256 + blk * 16 + m];
        const float b2i_ = BIAS[384 + blk * 16 + m];
#pragma unroll
        for (int r = 0; r < 4; r++) {
            float sr = Er[r] + b2r_, si = Ei[r] + b2i_;
            sr = (sr > LAM) ? (sr - LAM) : ((sr < -LAM) ? (sr + LAM) : 0.f);
            si = (si > LAM) ? (si - LAM) : ((si < -LAM) ? (si + LAM) : 0.f);
            pbase[(size_t)(kc * 4 + r) * CC + blk * 16 + m] =
                pack_c(make_float2(sr, si));
        }
    }
}

// ---------------- Pass 7: irfft along W + residual, two channels per inverse
// complex FFT (Z[k] = Xa[k] + i*Xb[k], Hermitian-extended; DC/Nyq imag zeroed
// to match C2R semantics).
__global__ __launch_bounds__(256) void k_irfft_w(const unsigned* __restrict__ buf,
                                                 const float* __restrict__ x,
                                                 float* __restrict__ out) {
    __shared__ float2 lds[32 * LROW];
    const int t = threadIdx.x;
    const size_t bdh = blockIdx.x;
    const unsigned* ip = buf + bdh * (size_t)(WR * CC);
    const float* xp = x + bdh * (size_t)(NDIM * CC);
    float* op = out + bdh * (size_t)(NDIM * CC);
    float2 tw[7];
    make_tw(t & 7, tw);
    for (int chunk = 0; chunk < 2; chunk++) {
        const int c0 = chunk * 64;
        for (int i = t; i < WR * 32; i += 256) {
            int p = i & 31, k = i >> 5;
            uint2 u = *(const uint2*)&ip[(size_t)k * CC + c0 + 2 * p];
            float2 Xa = unpack_c(u.x);
            float2 Xb = unpack_c(u.y);
            if (k == 0 || k == 32) { Xa.y = 0.f; Xb.y = 0.f; }
            lds[p * LROW + k] = make_float2(Xa.x - Xb.y, Xa.y + Xb.x);
            if (k >= 1 && k <= 31)
                lds[p * LROW + (64 - k)] = make_float2(Xa.x + Xb.y, Xb.x - Xa.y);
        }
        __syncthreads();
        fft64_lds<1>(&lds[(t >> 3) * LROW], t & 7, tw);
        __syncthreads();
#pragma unroll
        for (int k8 = 0; k8 < 8; k8++) {
            int idx = k8 * 256 + t;
            int p = idx & 31, w = idx >> 5;
            float2 z = lds[p * LROW + w];
            size_t gi = (size_t)w * CC + c0 + 2 * p;
            float2 xv = *(const float2*)&xp[gi];
            float2 o = make_float2(z.x * ORTHO + xv.x, z.y * ORTHO + xv.y);
            *(float2*)&op[gi] = o;
        }
        __syncthreads();
    }
}

extern "C" void kernel_launch(void* const* d_in, const int* in_sizes, int n_in,
                              void* d_out, int out_size, void* d_ws, size_t ws_size,
                              hipStream_t stream) {
    const float* x = (const float*)d_in[0];
    const float* w1 = (const float*)d_in[1];
    const float* b1 = (const float*)d_in[2];
    const float* w2 = (const float*)d_in[3];
    const float* b2 = (const float*)d_in[4];
    float* out = (float*)d_out;
    unsigned* buf = (unsigned*)d_ws;  // B*D*H*WR*C u32 = 138.4 MB (L3-resident)

    // 1) rfft along W (channel-pair packed)
    k_rfft_w<<<BB * NDIM * NDIM, 256, 0, stream>>>(x, buf);
    // 2) FFT along H: per (b,d,wr)
    k_fft_axis<-1><<<BB * NDIM * WR, 256, 0, stream>>>(buf, WR, S_Ds, S_WRs, S_Hs);
    // 3) FFT along D: per (b,h,wr)
    k_fft_axis<-1><<<BB * NDIM * WR, 256, 0, stream>>>(buf, NDIM * WR, S_Bs, S_WRs, S_Ds);
    // 4) block-diagonal complex MLP + softshrink via MFMA (64 points per CTA)
    k_mlp<<<(BB * NDIM * NDIM * WR) / 64, 256, 0, stream>>>(buf, w1, b1, w2, b2);
    // 5) inverse FFT along D
    k_fft_axis<1><<<BB * NDIM * WR, 256, 0, stream>>>(buf, NDIM * WR, S_Bs, S_WRs, S_Ds);
    // 6) inverse FFT along H
    k_fft_axis<1><<<BB * NDIM * WR, 256, 0, stream>>>(buf, WR, S_Ds, S_WRs, S_Hs);
    // 7) irfft along W + residual (channel-pair packed)
    k_irfft_w<<<BB * NDIM * NDIM, 256, 0, stream>>>(buf, x, out);
}